// Round 11
// baseline (354.563 us; speedup 1.0000x reference)
//
#include <hip/hip_runtime.h>
#include <stdint.h>

// Problem geometry
#define TR  2000   // real sequence length
#define TP  2048   // padded
#define NDF 4096   // D*F
#define NB  4      // batch

typedef __attribute__((ext_vector_type(8))) short short8;
typedef __attribute__((ext_vector_type(4))) float f32x4;

static __device__ __forceinline__ unsigned short f2bf(float f) {
  union { float f; unsigned u; } v; v.f = f;
  return (unsigned short)((v.u + 0x7fffu + ((v.u >> 16) & 1u)) >> 16);
}

typedef const __attribute__((address_space(1))) void CGV;
typedef __attribute__((address_space(3))) void LV;

static __device__ __forceinline__ void async16(const void* g, void* l) {
  __builtin_amdgcn_global_load_lds((CGV*)g, (LV*)l, 16, 0, 0);
}

// ---------------------------------------------------------------------------
// Prep 1: x (B, DF, TR) fp32 -> Xb (B, DF, TP) bf16 (pad cols zero)
//                            -> Vb (B, TP, DF) bf16 (transpose; pad rows zero)
__global__ void k_prep_xv(const float* __restrict__ x,
                          unsigned short* __restrict__ Xb,
                          unsigned short* __restrict__ Vb) {
  __shared__ float tile[32][33];
  const int b  = blockIdx.z;
  const int d0 = blockIdx.x * 32;
  const int t0 = blockIdx.y * 32;
  const int lx = threadIdx.x & 31;
  const int ly = threadIdx.x >> 5;
#pragma unroll
  for (int i = 0; i < 4; ++i) {
    const int d = d0 + ly + i * 8;
    const int t = t0 + lx;
    float v = 0.f;
    if (t < TR) v = x[((size_t)b * NDF + d) * TR + t];
    tile[ly + i * 8][lx] = v;
    Xb[((size_t)b * NDF + d) * TP + t] = f2bf(v);
  }
  __syncthreads();
#pragma unroll
  for (int i = 0; i < 4; ++i) {
    const int t = t0 + ly + i * 8;
    const int d = d0 + lx;
    Vb[((size_t)b * TP + t) * NDF + d] = f2bf(tile[lx][ly + i * 8]);
  }
}

// ---------------------------------------------------------------------------
// Prep 2: Qb (B, TP, DF) bf16 = e (B, DF) + sinusoidal PE(t, df)
__global__ void k_prep_q(const float* __restrict__ e,
                         unsigned short* __restrict__ Qb) {
  const int gid = blockIdx.x * 256 + threadIdx.x;
  const int t   = gid >> 9;
  const int d0  = (gid & 511) * 8;
  float pe[8];
#pragma unroll
  for (int p = 0; p < 4; ++p) {
    const float twoi = (float)(d0 + 2 * p);
    const float dv   = expf(twoi * (-9.210340371976184f / 4096.0f));
    const float ang  = (float)t * dv;
    pe[2 * p]     = sinf(ang);
    pe[2 * p + 1] = cosf(ang);
  }
#pragma unroll
  for (int b = 0; b < NB; ++b) {
    const float* ep = e + (size_t)b * NDF + d0;
    short8 sv;
#pragma unroll
    for (int j = 0; j < 8; ++j) sv[j] = (short)f2bf(ep[j] + pe[j]);
    *(short8*)(Qb + ((size_t)b * TP + t) * NDF + d0) = sv;
  }
}

// ---------------------------------------------------------------------------
// 256x256 GEMM (B^T form): C[m][n] = sum_k A[m][k]*Bt[n][k].
// 512 thr = 8 waves (2M x 4N), per-wave 128x64, BK=64, dbuf LDS 128 KiB.
//
// m201 8-phase template (round-10, passing) + ROUND-11 CHANGE: MFMA clusters
// are K-SLOT-OUTER — all 8 independent k0 MFMAs, then the 8 k1 MFMAs (each
// dependent MFMA is 8 instructions (~39 cyc) from its producer, vs adjacent
// in round 10). With 2 waves/SIMD (1 block/CU), adjacent dependent pairs
// stall the MFMA pipe at ~latency rate; this reorder restores issue rate.
//
// Per K-tile kt (cur buf cb, next cbn):
//   Ph0: rd afLo(kt),bf01(kt) [12]; stage A1(kt+1)->cbn; lgk(8); B;lgk0; Q00; B
//   Ph1: rd bf23(kt) [4];                                 B;lgk0; Q01; B
//   Ph2: rd afHi(kt) [8]; stage B0,B1(kt+2)->cb;          B;lgk0; Q10; B
//   Ph3: stage A0(kt+2)->cb;                              B; Q11; vmc(6); B
//
// WAR/RAW ledgers as round 10 (verified passing).
template <int LDK, bool GUARD>
__launch_bounds__(512, 2)
__global__ void k_gemm256(const unsigned short* __restrict__ A,
                          const unsigned short* __restrict__ Bt,
                          float* __restrict__ C,
                          size_t sA, size_t sB, size_t sC,
                          int ldc, int ncols) {
  __shared__ unsigned short lds[65536];   // 2 bufs x (A 16K elem | B 16K elem)
  constexpr int NT = LDK / 64;            // K-tiles, >= 4
  const int b  = blockIdx.z;
  const int m0 = blockIdx.x * 256;
  const int n0 = blockIdx.y * 256;
  const unsigned short* Ab = A + (size_t)b * sA;
  const unsigned short* Bb = Bt + (size_t)b * sB;
  const int t = threadIdx.x, w = t >> 6, l = t & 63;
  const int wm = w >> 2, wn = w & 3;
  const int lr = l & 15, lg = l >> 4;

  // staging source (inverse-swizzled global col: LDS 16B-slot s of row r
  // holds global slot s^(r&7))
  const int rofs = w * 8 + (l >> 3);
  const int csw  = ((l & 7) ^ ((l >> 3) & 7)) * 8;
  const unsigned short* gA = Ab + (size_t)(m0 + rofs) * LDK + csw;
  const unsigned short* gB = Bb + (size_t)(n0 + rofs) * LDK + csw;

#define STAGE(cb, isB, h, kt) do {                                           \
    const unsigned short* _g = ((isB) ? gB : gA)                             \
                               + (size_t)((h) * 128) * LDK + (size_t)(kt) * 64; \
    unsigned short* _d = lds + (cb) + (isB) * 16384 + (h) * 8192 + w * 512;  \
    async16(_g, _d);                                                         \
    async16(_g + (size_t)64 * LDK, _d + 4096);                               \
  } while (0)

  // swizzled k-slot offsets (elements) for ks=0,1
  const int s0 = ((0 + lg) ^ (lr & 7)) * 8;
  const int s1 = ((4 + lg) ^ (lr & 7)) * 8;
  const int aoff = wm * 8192 + lr * 64;                              // A base
  const int boff = 16384 + (wn >> 1) * 8192 + ((wn & 1) * 64 + lr) * 64; // B

#define SCHED0 __builtin_amdgcn_sched_barrier(0)
#define PB do { SCHED0; __builtin_amdgcn_s_barrier(); SCHED0; } while (0)
#define VMC(n) do { asm volatile("s_waitcnt vmcnt(" #n ")"); SCHED0; } while (0)
#define LGK(n) do { asm volatile("s_waitcnt lgkmcnt(" #n ")"); SCHED0; } while (0)
#define RD_A(dst, base, off) do {                                            \
    _Pragma("unroll")                                                        \
    for (int f = 0; f < 4; ++f) {                                            \
      dst[f][0] = *(const short8*)((base) + ((off) + f) * 1024 + s0);        \
      dst[f][1] = *(const short8*)((base) + ((off) + f) * 1024 + s1);        \
    } } while (0)
#define RD_B(dst, base, off) do {                                            \
    _Pragma("unroll")                                                        \
    for (int f = 0; f < 2; ++f) {                                            \
      dst[f][0] = *(const short8*)((base) + ((off) + f) * 1024 + s0);        \
      dst[f][1] = *(const short8*)((base) + ((off) + f) * 1024 + s1);        \
    } } while (0)
// k-slot-outer MFMA cluster: 8 independent MFMAs (ks=0), then 8 (ks=1).
#define MM(I0, J0, AFV, BFV) do {                                            \
    __builtin_amdgcn_s_setprio(1);                                           \
    _Pragma("unroll")                                                        \
    for (int ks = 0; ks < 2; ++ks)                                           \
      _Pragma("unroll")                                                      \
      for (int i = 0; i < 4; ++i)                                            \
        _Pragma("unroll")                                                    \
        for (int j = 0; j < 2; ++j)                                          \
          acc[(I0) + i][(J0) + j] = __builtin_amdgcn_mfma_f32_16x16x32_bf16( \
              AFV[i][ks], BFV[j][ks], acc[(I0) + i][(J0) + j], 0, 0, 0);     \
    __builtin_amdgcn_s_setprio(0); } while (0)

  short8 afLo[4][2], afHi[4][2], bf01[2][2], bf23[2][2];
  f32x4 acc[8][4] = {};

  // ---- prologue: kt0 fully + A0,B0,B1(1) (14 loads); retire kt0's 8.
  STAGE(0, 0, 0, 0);            // A0(0)
  STAGE(0, 0, 1, 0);            // A1(0)
  STAGE(0, 1, 0, 0);            // B0(0)
  STAGE(0, 1, 1, 0);            // B1(0)
  STAGE(32768, 0, 0, 1);        // A0(1)
  STAGE(32768, 1, 0, 1);        // B0(1)
  STAGE(32768, 1, 1, 1);        // B1(1)
  VMC(6);
  PB;

  auto ktile = [&](int kt, bool nx, bool pf2) __attribute__((always_inline)) {
    const int cb  = (kt & 1) << 15;       // current buf (element offset)
    const int cbn = cb ^ 32768;           // next buf
    const unsigned short* la = lds + cb + aoff;
    const unsigned short* lb = lds + cb + boff;

    // Ph0: rd afLo(kt), bf01(kt); stage A1(kt+1)->cbn
    RD_A(afLo, la, 0);
    RD_B(bf01, lb, 0);
    if (nx) STAGE(cbn, 0, 1, kt + 1);
    LGK(8);                      // throttle (12-read phase, per template)
    PB;
    LGK(0);
    MM(0, 0, afLo, bf01);
    PB;

    // Ph1: rd bf23(kt)
    RD_B(bf23, lb, 2);
    PB;
    LGK(0);
    MM(0, 2, afLo, bf23);
    PB;

    // Ph2: rd afHi(kt); stage B0,B1(kt+2)->cb
    RD_A(afHi, la, 4);
    if (pf2) { STAGE(cb, 1, 0, kt + 2); STAGE(cb, 1, 1, kt + 2); }
    PB;
    LGK(0);
    MM(4, 0, afHi, bf01);
    PB;

    // Ph3: stage A0(kt+2)->cb; Q11; counted gate (once per K-tile)
    if (pf2) STAGE(cb, 0, 0, kt + 2);
    PB;
    MM(4, 2, afHi, bf23);
    if (nx) { if (pf2) VMC(6); else VMC(0); }
    PB;
  };

  for (int kt = 0; kt < NT - 2; ++kt) ktile(kt, true, true);
  ktile(NT - 2, true, false);
  ktile(NT - 1, false, false);

#undef STAGE
#undef RD_A
#undef RD_B
#undef MM
#undef PB
#undef SCHED0
#undef VMC
#undef LGK

  // epilogue: C/D layout col=lane&15, row=(lane>>4)*4+reg (m89-verified)
  float* Cb = C + (size_t)b * sC;
#pragma unroll
  for (int i = 0; i < 8; ++i) {
    const int rb = m0 + wm * 128 + i * 16 + lg * 4;
#pragma unroll
    for (int f = 0; f < 4; ++f) {
      const int cg = n0 + wn * 64 + f * 16 + lr;
      if (!GUARD || cg < ncols) {
#pragma unroll
        for (int j = 0; j < 4; ++j)
          Cb[(size_t)(rb + j) * ldc + cg] = acc[i][f][j];
      }
    }
  }
}

// ---------------------------------------------------------------------------
// Row softmax: P[i][j] = softmax_j(S[i][0..TR)/64), bf16 out, pad zeroed.
__global__ void k_softmax(const float* __restrict__ S,
                          unsigned short* __restrict__ P) {
  const int i = blockIdx.x;
  const int b = blockIdx.y;
  unsigned short* prow = P + ((size_t)b * TP + i) * TP;
  const int t = threadIdx.x;
  if (i >= TR) {
    for (int j = t; j < TP; j += 256) prow[j] = 0;
    return;
  }
  const float* srow = S + ((size_t)b * TP + i) * TP;
  float v[8];
  float mx = -1e30f;
#pragma unroll
  for (int r = 0; r < 8; ++r) {
    const int j = t + r * 256;
    const float s = (j < TR) ? srow[j] * 0.015625f : -1e30f;
    v[r] = s;
    mx = fmaxf(mx, s);
  }
  __shared__ float red[4];
#pragma unroll
  for (int off = 32; off > 0; off >>= 1) mx = fmaxf(mx, __shfl_xor(mx, off));
  if ((t & 63) == 0) red[t >> 6] = mx;
  __syncthreads();
  mx = fmaxf(fmaxf(red[0], red[1]), fmaxf(red[2], red[3]));
  __syncthreads();
  float sum = 0.f;
#pragma unroll
  for (int r = 0; r < 8; ++r) {
    const float ev = __expf(v[r] - mx);
    v[r] = ev;
    sum += ev;
  }
#pragma unroll
  for (int off = 32; off > 0; off >>= 1) sum += __shfl_xor(sum, off);
  if ((t & 63) == 0) red[t >> 6] = sum;
  __syncthreads();
  sum = red[0] + red[1] + red[2] + red[3];
  const float inv = 1.f / sum;
#pragma unroll
  for (int r = 0; r < 8; ++r) {
    const int j = t + r * 256;
    prow[j] = (j < TR) ? f2bf(v[r] * inv) : (unsigned short)0;
  }
}

// ---------------------------------------------------------------------------
extern "C" void kernel_launch(void* const* d_in, const int* in_sizes, int n_in,
                              void* d_out, int out_size, void* d_ws, size_t ws_size,
                              hipStream_t stream) {
  const float* x = (const float*)d_in[0];   // (B, DF, TR)
  const float* e = (const float*)d_in[1];   // (B, DF)
  float* out = (float*)d_out;               // (B, DF, TR)
  char* ws = (char*)d_ws;

  const size_t szQ = (size_t)NB * TP * NDF * 2;
  const size_t szV = szQ;
  const size_t szX = szQ;
  const size_t szS = (size_t)NB * TP * TP * 4;
  const size_t szP = (size_t)NB * TP * TP * 2;
  if (ws_size < szQ + szV + szX + szS + szP) return;

  unsigned short* Qb = (unsigned short*)(ws);
  unsigned short* Vb = (unsigned short*)(ws + szQ);
  unsigned short* Xb = (unsigned short*)(ws + szQ + szV);
  float*          S  = (float*)(ws + szQ + szV + szX);
  unsigned short* P  = (unsigned short*)(ws + szQ + szV + szX + szS);

  // 1) cast + transpose x
  k_prep_xv<<<dim3(NDF / 32, TP / 32, NB), 256, 0, stream>>>(x, Xb, Vb);
  // 2) Q = e + PE
  k_prep_q<<<dim3((TP * (NDF / 8)) / 256), 256, 0, stream>>>(e, Qb);
  // 3) S = Q * V^T   (M=TP, N=TP, K=NDF)
  k_gemm256<NDF, false><<<dim3(TP / 256, TP / 256, NB), 512, 0, stream>>>(
      Qb, Vb, S,
      (size_t)TP * NDF, (size_t)TP * NDF, (size_t)TP * TP, TP, TP);
  // 4) P = softmax(S/64)
  k_softmax<<<dim3(TP, NB), 256, 0, stream>>>(S, P);
  // 5) att^T = X * P^T  (M=NDF, N=TP, K=TP), store cols < TR
  k_gemm256<TP, true><<<dim3(NDF / 256, TP / 256, NB), 512, 0, stream>>>(
      Xb, P, out,
      (size_t)NDF * TP, (size_t)TP * TP, (size_t)NDF * TR, TR, TR);
}

// Round 12
// 340.508 us; speedup vs baseline: 1.0413x; 1.0413x over previous
//
#include <hip/hip_runtime.h>
#include <stdint.h>

// Problem geometry
#define TR  2000   // real sequence length
#define TP  2048   // padded
#define NDF 4096   // D*F
#define NB  4      // batch

typedef __attribute__((ext_vector_type(8))) short short8;
typedef __attribute__((ext_vector_type(4))) float f32x4;

static __device__ __forceinline__ unsigned short f2bf(float f) {
  union { float f; unsigned u; } v; v.f = f;
  return (unsigned short)((v.u + 0x7fffu + ((v.u >> 16) & 1u)) >> 16);
}

typedef const __attribute__((address_space(1))) void CGV;
typedef __attribute__((address_space(3))) void LV;

static __device__ __forceinline__ void async16(const void* g, void* l) {
  __builtin_amdgcn_global_load_lds((CGV*)g, (LV*)l, 16, 0, 0);
}

// ---------------------------------------------------------------------------
// Prep 1: x (B, DF, TR) fp32 -> Xb (B, DF, TP) bf16 (pad cols zero)
//                            -> Vb (B, TP, DF) bf16 (transpose; pad rows zero)
//                            -> up[dblk, b, t] = sum_{d in dblk} e[b,d]*x[b,d,t]
// (u partials: deterministic, no atomics; reduced by k_sum_u)
__global__ void k_prep_xv(const float* __restrict__ x,
                          const float* __restrict__ e,
                          unsigned short* __restrict__ Xb,
                          unsigned short* __restrict__ Vb,
                          float* __restrict__ up) {
  __shared__ float tile[32][33];
  __shared__ float ured[8][32];
  const int b  = blockIdx.z;
  const int d0 = blockIdx.x * 32;
  const int t0 = blockIdx.y * 32;
  const int lx = threadIdx.x & 31;
  const int ly = threadIdx.x >> 5;
  float us = 0.f;
#pragma unroll
  for (int i = 0; i < 4; ++i) {
    const int d = d0 + ly + i * 8;
    const int t = t0 + lx;
    float v = 0.f;
    if (t < TR) v = x[((size_t)b * NDF + d) * TR + t];
    tile[ly + i * 8][lx] = v;
    Xb[((size_t)b * NDF + d) * TP + t] = f2bf(v);
    us += e[(size_t)b * NDF + d] * v;
  }
  ured[ly][lx] = us;
  __syncthreads();
#pragma unroll
  for (int i = 0; i < 4; ++i) {
    const int t = t0 + ly + i * 8;
    const int d = d0 + lx;
    Vb[((size_t)b * TP + t) * NDF + d] = f2bf(tile[lx][ly + i * 8]);
  }
  if (threadIdx.x < 32) {
    float s = 0.f;
#pragma unroll
    for (int r = 0; r < 8; ++r) s += ured[r][threadIdx.x];
    up[(size_t)blockIdx.x * (NB * TP) + (size_t)b * TP + t0 + threadIdx.x] = s;
  }
}

// Reduce u[b,t] = sum over 128 d-blocks of up
__global__ void k_sum_u(const float* __restrict__ up, float* __restrict__ u) {
  const int idx = blockIdx.x * 256 + threadIdx.x;   // b*TP + t
  float s = 0.f;
#pragma unroll 8
  for (int i = 0; i < NDF / 32; ++i) s += up[(size_t)i * (NB * TP) + idx];
  u[idx] = s;
}

// ---------------------------------------------------------------------------
// Prep 2: PEb (TP, NDF) bf16 = sinusoidal PE(t, df)  (batch-shared GEMM1 A)
__global__ void k_prep_pe(unsigned short* __restrict__ PEb) {
  const int gid = blockIdx.x * 256 + threadIdx.x;
  const int t   = gid >> 9;
  const int d0  = (gid & 511) * 8;
  short8 sv;
#pragma unroll
  for (int p = 0; p < 4; ++p) {
    const float twoi = (float)(d0 + 2 * p);
    const float dv   = expf(twoi * (-9.210340371976184f / 4096.0f));
    const float ang  = (float)t * dv;
    sv[2 * p]     = (short)f2bf(sinf(ang));
    sv[2 * p + 1] = (short)f2bf(cosf(ang));
  }
  *(short8*)(PEb + (size_t)t * NDF + d0) = sv;
}

// ---------------------------------------------------------------------------
// 256x256 GEMM (B^T form): C[m][n] = sum_k A[m][k]*Bt[n][k].
// ROUND-4 VERBATIM (best measured: ~140 us/GEMM, MfmaUtil 43%, passed).
// 512 thr = 8 waves (2M x 4N), per-wave 128x64, BK=64, dbuf LDS 128 KiB.
// One barrier per phase; counted vmcnt(6)/(4) with 2-4 phase landing windows;
// bf01 read-ahead; setprio(1) around each 16-MFMA cluster; T2 xor-swizzle.
// sA=0 makes A batch-shared (GEMM1: A = PE).
template <int LDK, bool GUARD>
__launch_bounds__(512, 2)
__global__ void k_gemm256(const unsigned short* __restrict__ A,
                          const unsigned short* __restrict__ Bt,
                          float* __restrict__ C,
                          size_t sA, size_t sB, size_t sC,
                          int ldc, int ncols) {
  __shared__ unsigned short lds[65536];   // [buf2][A(16K elem)|B(16K elem)]
  constexpr int NT = LDK / 64;            // K-tiles, even, >= 4
  const int b  = blockIdx.z;
  const int m0 = blockIdx.x * 256;
  const int n0 = blockIdx.y * 256;
  const unsigned short* Ab = A + (size_t)b * sA;
  const unsigned short* Bb = Bt + (size_t)b * sB;
  const int t = threadIdx.x, w = t >> 6, l = t & 63;
  const int wm = w >> 2, wn = w & 3;
  const int lr = l & 15, lg = l >> 4;

  const int rofs = w * 8 + (l >> 3);
  const int csw  = ((l & 7) ^ ((l >> 3) & 7)) * 8;
  const unsigned short* gA = Ab + (size_t)(m0 + rofs) * LDK + csw;
  const unsigned short* gB = Bb + (size_t)(n0 + rofs) * LDK + csw;

#define STAGE(c, isB, h, kt) do {                                            \
    const unsigned short* _g = ((isB) ? gB : gA)                             \
                               + (size_t)((h) * 128) * LDK + (size_t)(kt) * 64; \
    unsigned short* _d = lds + (c) * 32768 + (isB) * 16384 + (h) * 8192      \
                         + w * 512;                                          \
    async16(_g, _d);                                                         \
    async16(_g + (size_t)64 * LDK, _d + 4096);                               \
  } while (0)

  const unsigned short* laA[2] = { lds + wm * 8192 + lr * 64,
                                   lds + 32768 + wm * 8192 + lr * 64 };
  const unsigned short* lbB[2] = { lds + 16384 + (wn >> 1) * 8192 + ((wn & 1) * 64 + lr) * 64,
                                   lds + 49152 + (wn >> 1) * 8192 + ((wn & 1) * 64 + lr) * 64 };
  const int s0 = ((0 + lg) ^ (lr & 7)) * 8;
  const int s1 = ((4 + lg) ^ (lr & 7)) * 8;

#define PB do { asm volatile("" ::: "memory");                               \
                __builtin_amdgcn_s_barrier();                                \
                asm volatile("" ::: "memory"); } while (0)
#define VMC(n) asm volatile("s_waitcnt vmcnt(" #n ")" ::: "memory")
#define RD_A(base, off) do {                                                 \
    _Pragma("unroll")                                                        \
    for (int f = 0; f < 4; ++f) {                                            \
      af[f][0] = *(const short8*)((base) + ((off) + f) * 1024 + s0);         \
      af[f][1] = *(const short8*)((base) + ((off) + f) * 1024 + s1);         \
    } } while (0)
#define RD_B(dst, base, off) do {                                            \
    _Pragma("unroll")                                                        \
    for (int f = 0; f < 2; ++f) {                                            \
      dst[f][0] = *(const short8*)((base) + ((off) + f) * 1024 + s0);        \
      dst[f][1] = *(const short8*)((base) + ((off) + f) * 1024 + s1);        \
    } } while (0)
#define MM(I0, J0, BFV) do {                                                 \
    __builtin_amdgcn_s_setprio(1);                                           \
    _Pragma("unroll")                                                        \
    for (int i = 0; i < 4; ++i)                                              \
      _Pragma("unroll")                                                      \
      for (int j = 0; j < 2; ++j) {                                          \
        acc[(I0) + i][(J0) + j] = __builtin_amdgcn_mfma_f32_16x16x32_bf16(   \
            af[i][0], BFV[j][0], acc[(I0) + i][(J0) + j], 0, 0, 0);          \
        acc[(I0) + i][(J0) + j] = __builtin_amdgcn_mfma_f32_16x16x32_bf16(   \
            af[i][1], BFV[j][1], acc[(I0) + i][(J0) + j], 0, 0, 0);          \
      }                                                                      \
    __builtin_amdgcn_s_setprio(0); } while (0)

  short8 af[4][2], bf01[2][2], bf23[2][2];
  f32x4 acc[8][4] = {};

  // prologue: kt0 fully staged (buf0), B(kt1) in flight (buf1)
  STAGE(0, 0, 0, 0); STAGE(0, 0, 1, 0); STAGE(0, 1, 0, 0); STAGE(0, 1, 1, 0);
  STAGE(1, 1, 0, 1); STAGE(1, 1, 1, 1);
  VMC(4);
  PB;
  RD_B(bf01, lbB[0], 0);

  for (int i2 = 0; i2 < NT / 2; ++i2) {
    const int kt0 = 2 * i2, kt1 = kt0 + 1;
    const bool pf = (kt0 + 2 < NT);

    // P0
    RD_A(laA[0], 0);
    STAGE(1, 0, 0, kt1);
    MM(0, 0, bf01);
    PB;
    // P1
    RD_B(bf23, lbB[0], 2);
    STAGE(1, 0, 1, kt1);
    MM(0, 2, bf23);
    PB;
    // P2
    RD_A(laA[0], 4);
    if (pf) STAGE(0, 1, 0, kt0 + 2);
    MM(4, 0, bf01);
    if (pf) VMC(6); else VMC(0);
    PB;
    // P3
    RD_B(bf01, lbB[1], 0);
    if (pf) STAGE(0, 1, 1, kt0 + 2);
    MM(4, 2, bf23);
    if (pf) VMC(4); else VMC(0);
    PB;
    // P4
    RD_A(laA[1], 0);
    if (pf) STAGE(0, 0, 0, kt0 + 2);
    MM(0, 0, bf01);
    PB;
    // P5
    RD_B(bf23, lbB[1], 2);
    if (pf) STAGE(0, 0, 1, kt0 + 2);
    MM(0, 2, bf23);
    PB;
    // P6
    RD_A(laA[1], 4);
    if (pf) STAGE(1, 1, 0, kt1 + 2);
    MM(4, 0, bf01);
    if (pf) VMC(6);
    PB;
    // P7
    if (pf) RD_B(bf01, lbB[0], 0);
    if (pf) STAGE(1, 1, 1, kt1 + 2);
    MM(4, 2, bf23);
    if (pf) VMC(4);
    PB;
  }
#undef STAGE
#undef RD_A
#undef RD_B
#undef MM
#undef PB
#undef VMC

  // epilogue: C/D layout col=lane&15, row=(lane>>4)*4+reg (m89-verified)
  float* Cb = C + (size_t)b * sC;
#pragma unroll
  for (int i = 0; i < 8; ++i) {
    const int rb = m0 + wm * 128 + i * 16 + lg * 4;
#pragma unroll
    for (int f = 0; f < 4; ++f) {
      const int cg = n0 + wn * 64 + f * 16 + lr;
      if (!GUARD || cg < ncols) {
#pragma unroll
        for (int j = 0; j < 4; ++j)
          Cb[(size_t)(rb + j) * ldc + cg] = acc[i][f][j];
      }
    }
  }
}

// ---------------------------------------------------------------------------
// Row softmax: P[i][j] = softmax_j((S[i][j] + u[j]) / 64), bf16 out, pad 0.
__global__ void k_softmax(const float* __restrict__ S,
                          const float* __restrict__ u,
                          unsigned short* __restrict__ P) {
  const int i = blockIdx.x;
  const int b = blockIdx.y;
  unsigned short* prow = P + ((size_t)b * TP + i) * TP;
  const int t = threadIdx.x;
  if (i >= TR) {
    for (int j = t; j < TP; j += 256) prow[j] = 0;
    return;
  }
  const float* srow = S + ((size_t)b * TP + i) * TP;
  const float* ub   = u + (size_t)b * TP;
  float v[8];
  float mx = -1e30f;
#pragma unroll
  for (int r = 0; r < 8; ++r) {
    const int j = t + r * 256;
    const float s = (j < TR) ? (srow[j] + ub[j]) * 0.015625f : -1e30f;
    v[r] = s;
    mx = fmaxf(mx, s);
  }
  __shared__ float red[4];
#pragma unroll
  for (int off = 32; off > 0; off >>= 1) mx = fmaxf(mx, __shfl_xor(mx, off));
  if ((t & 63) == 0) red[t >> 6] = mx;
  __syncthreads();
  mx = fmaxf(fmaxf(red[0], red[1]), fmaxf(red[2], red[3]));
  __syncthreads();
  float sum = 0.f;
#pragma unroll
  for (int r = 0; r < 8; ++r) {
    const float ev = __expf(v[r] - mx);
    v[r] = ev;
    sum += ev;
  }
#pragma unroll
  for (int off = 32; off > 0; off >>= 1) sum += __shfl_xor(sum, off);
  if ((t & 63) == 0) red[t >> 6] = sum;
  __syncthreads();
  sum = red[0] + red[1] + red[2] + red[3];
  const float inv = 1.f / sum;
#pragma unroll
  for (int r = 0; r < 8; ++r) {
    const int j = t + r * 256;
    prow[j] = (j < TR) ? f2bf(v[r] * inv) : (unsigned short)0;
  }
}

// ---------------------------------------------------------------------------
extern "C" void kernel_launch(void* const* d_in, const int* in_sizes, int n_in,
                              void* d_out, int out_size, void* d_ws, size_t ws_size,
                              hipStream_t stream) {
  const float* x = (const float*)d_in[0];   // (B, DF, TR)
  const float* e = (const float*)d_in[1];   // (B, DF)
  float* out = (float*)d_out;               // (B, DF, TR)
  char* ws = (char*)d_ws;

  const size_t szPE = (size_t)TP * NDF * 2;        // 16.8 MB
  const size_t szV  = (size_t)NB * TP * NDF * 2;   // 67 MB
  const size_t szX  = szV;                          // 67 MB
  const size_t szS  = (size_t)NB * TP * TP * 4;    // 67 MB
  const size_t szP  = (size_t)NB * TP * TP * 2;    // 33.5 MB
  const size_t szUP = (size_t)(NDF / 32) * NB * TP * 4;  // 4 MB
  const size_t szU  = (size_t)NB * TP * 4;          // 32 KB
  if (ws_size < szPE + szV + szX + szS + szP + szUP + szU) return;

  unsigned short* PEb = (unsigned short*)(ws);
  unsigned short* Vb  = (unsigned short*)(ws + szPE);
  unsigned short* Xb  = (unsigned short*)(ws + szPE + szV);
  float*          S   = (float*)(ws + szPE + szV + szX);
  unsigned short* P   = (unsigned short*)(ws + szPE + szV + szX + szS);
  float*          up  = (float*)(ws + szPE + szV + szX + szS + szP);
  float*          u   = (float*)(ws + szPE + szV + szX + szS + szP + szUP);

  // 1) cast + transpose x, accumulate u partials
  k_prep_xv<<<dim3(NDF / 32, TP / 32, NB), 256, 0, stream>>>(x, e, Xb, Vb, up);
  // 2) u = sum of partials
  k_sum_u<<<dim3(NB * TP / 256), 256, 0, stream>>>(up, u);
  // 3) PE table (batch-shared)
  k_prep_pe<<<dim3((TP * (NDF / 8)) / 256), 256, 0, stream>>>(PEb);
  // 4) W = PE * V^T   (M=TP, N=TP, K=NDF), A batch-shared (sA=0)
  k_gemm256<NDF, false><<<dim3(TP / 256, TP / 256, NB), 512, 0, stream>>>(
      PEb, Vb, S,
      0, (size_t)TP * NDF, (size_t)TP * TP, TP, TP);
  // 5) P = softmax((W + u)/64)
  k_softmax<<<dim3(TP, NB), 256, 0, stream>>>(S, u, P);
  // 6) att^T = X * P^T  (M=NDF, N=TP, K=TP), store cols < TR
  k_gemm256<TP, true><<<dim3(NDF / 256, TP / 256, NB), 512, 0, stream>>>(
      Xb, P, out,
      (size_t)NDF * TP, (size_t)TP * TP, (size_t)NDF * TR, TR, TR);
}